// Round 6
// baseline (204.336 us; speedup 1.0000x reference)
//
#include <hip/hip_runtime.h>

#define HH 192
#define WW 192
#define LL (HH * WW)   // 36864
#define CC 512
#define KK 64
#define EPSF 1e-12f
typedef unsigned long long ull;
typedef unsigned int uint;
typedef unsigned short ushort;

// k3 decomposition
#define NCHUNK 192
#define CHUNKL (LL / NCHUNK)   // 192

typedef short bf16x8 __attribute__((ext_vector_type(8)));
typedef float f32x4 __attribute__((ext_vector_type(4)));

// ---------------------------------------------------------------- async global->LDS, 16B per lane
__device__ __forceinline__ void gl16(const float* g, float* l) {
    __builtin_amdgcn_global_load_lds((const __attribute__((address_space(1))) void*)g,
                                     (__attribute__((address_space(3))) void*)l, 16, 0, 0);
}

// ---------------------------------------------------------------- fp32 -> 3-way bf16 split (hi/mid/lo, truncation; exact residuals)
__device__ inline void split3(float v, ushort& h, ushort& md, ushort& lo) {
    uint b  = __float_as_uint(v);
    uint hb = b & 0xFFFF0000u;
    float r1 = v - __uint_as_float(hb);          // exact
    uint mb = __float_as_uint(r1) & 0xFFFF0000u;
    float r2 = r1 - __uint_as_float(mb);         // exact
    uint lb = __float_as_uint(r2) & 0xFFFF0000u;
    h = (ushort)(hb >> 16); md = (ushort)(mb >> 16); lo = (ushort)(lb >> 16);
}

// ---------------------------------------------------------------- fp32 -> 2-way bf16 split (hi + residual lo)
__device__ inline void split2(float v, ushort& h, ushort& lo) {
    uint b  = __float_as_uint(v);
    uint hb = b & 0xFFFF0000u;
    float r = v - __uint_as_float(hb);           // exact
    h = (ushort)(hb >> 16); lo = (ushort)(__float_as_uint(r) >> 16);
}

// ---------------------------------------------------------------- k0: pre-split conv_w into fragment-ordered bf16 hi/mid/lo arrays.
// Fragment order: element W[kg*16+m][s*32 + quad*8 + j] -> ushort index ((s*4+kg)*64 + quad*16 + m)*8 + j
// so a wave's A-frag for (s,kg) is one coalesced 16B/lane load at base + ((s*4+kg)*64 + lane)*8.
__global__ __launch_bounds__(256) void k0_prep(const float* __restrict__ w,
                                               ushort* __restrict__ Whi,
                                               ushort* __restrict__ Wmid,
                                               ushort* __restrict__ Wlo,
                                               float* __restrict__ Szero) {
    int idx = blockIdx.x * 256 + threadIdx.x;   // 32768 = KK*CC
    int k = idx >> 9;
    int c = idx & 511;
    int s = c >> 5, w32 = c & 31, quad = w32 >> 3, j = w32 & 7;
    int kg = k >> 4, m = k & 15;
    int dst = (((s * 4 + kg) * 4 + quad) * 16 + m) * 8 + j;
    float v = w[idx];
    ushort h, md, lo;
    split3(v, h, md, lo);
    Whi[dst] = h; Wmid[dst] = md; Wlo[dst] = lo;
    if (blockIdx.x == 0 && threadIdx.x < 128) Szero[threadIdx.x] = 0.f;  // S[64]+rowsq[64]
}

// ---------------------------------------------------------------- k1: MFMA logits GEMM + fused norm/softmax/top2.
// v5: fully-coalesced x path. 576 blocks x 256 thr (4 waves). Block owns 64 px; wave w owns
// px [pb+16w, pb+16w+16) and contracts the FULL c=512 itself (no cross-wave combine).
// Per 32-c step: stage x[32c][64px] (8 KB) to LDS via global_load_lds width-16 (each wave
// moves 4 contiguous 256B rows), double-buffered; barrier's vmcnt-drain gives the prefetch a
// whole compute phase to land. B-frags from LDS (8 ds_read_b32, <=4-way conflict); A-frags
// direct global b128 (same addrs across waves -> L1 dedup).
// 6-term triple-bf16 MFMA => ~2^-24 rel err (fp32-equivalent) so top-2 SET selection is stable.
__global__ __launch_bounds__(256) void k1_logits(const float* __restrict__ x,
                                                 const ushort* __restrict__ Whi,
                                                 const ushort* __restrict__ Wmid,
                                                 const ushort* __restrict__ Wlo,
                                                 float* __restrict__ soft,
                                                 float* __restrict__ invn,
                                                 ull* __restrict__ keep) {
    __shared__ float xs[2][32][64];    // 16 KB: double-buffered x tile [c-row][px]
    int t = threadIdx.x, lane = t & 63, wid = t >> 6;   // wid 0..3 = px-group
    int m = lane & 15, quad = lane >> 4;
    int pb = blockIdx.x * 64;

    f32x4 acc[4];
#pragma unroll
    for (int kg = 0; kg < 4; ++kg) acc[kg] = (f32x4){0.f, 0.f, 0.f, 0.f};
    float ss = 0.f;

    // wave w stages rows [4w,4w+4) and [16+4w,16+4w+4) of the 32-row step tile
    const float* gbase = x + (size_t)(4 * wid + quad) * LL + pb + m * 4;

    // ---- prologue: stage step 0 into buf 0 ----
    gl16(gbase, &xs[0][4 * wid][0]);
    gl16(gbase + (size_t)16 * LL, &xs[0][16 + 4 * wid][0]);

    int cur = 0;
#pragma unroll
    for (int s = 0; s < 16; ++s) {
        __syncthreads();   // drains vmcnt: buf[cur] staged; prev reads of buf[cur^1] done
        if (s < 15) {
            const float* g = gbase + (size_t)(s + 1) * 32 * LL;
            gl16(g, &xs[cur ^ 1][4 * wid][0]);
            gl16(g + (size_t)16 * LL, &xs[cur ^ 1][16 + 4 * wid][0]);
        }
        // ---- A frags: one b128/lane per (kg, plane), L2/L1-hot ----
        bf16x8 Ah[4], Am[4], Al[4];
#pragma unroll
        for (int kg = 0; kg < 4; ++kg) {
            size_t off = (size_t)(((s * 4 + kg) * 64 + lane) * 8);
            Ah[kg] = *(const bf16x8*)(Whi  + off);
            Am[kg] = *(const bf16x8*)(Wmid + off);
            Al[kg] = *(const bf16x8*)(Wlo  + off);
        }
        // ---- B frag from LDS: lane (m,quad) reads x[quad*8+j][wid*16+m] ----
        float xv[8];
#pragma unroll
        for (int j = 0; j < 8; ++j) xv[j] = xs[cur][quad * 8 + j][wid * 16 + m];
        bf16x8 Bh, Bm, Bl;
#pragma unroll
        for (int j = 0; j < 8; ++j) {
            float v = xv[j];
            ss = fmaf(v, v, ss);
            ushort h, md, lo;
            split3(v, h, md, lo);
            Bh[j] = (short)h; Bm[j] = (short)md; Bl[j] = (short)lo;
        }
        // ---- 6-term MFMA: hh + hm + mh + hl + lh + mm ----
#pragma unroll
        for (int kg = 0; kg < 4; ++kg) {
            f32x4 a = acc[kg];
            a = __builtin_amdgcn_mfma_f32_16x16x32_bf16(Ah[kg], Bh, a, 0, 0, 0);
            a = __builtin_amdgcn_mfma_f32_16x16x32_bf16(Ah[kg], Bm, a, 0, 0, 0);
            a = __builtin_amdgcn_mfma_f32_16x16x32_bf16(Am[kg], Bh, a, 0, 0, 0);
            a = __builtin_amdgcn_mfma_f32_16x16x32_bf16(Ah[kg], Bl, a, 0, 0, 0);
            a = __builtin_amdgcn_mfma_f32_16x16x32_bf16(Al[kg], Bh, a, 0, 0, 0);
            a = __builtin_amdgcn_mfma_f32_16x16x32_bf16(Am[kg], Bm, a, 0, 0, 0);
            acc[kg] = a;
        }
        cur ^= 1;
    }

    // ---- epilogue: wave-local (each wave owns its 16 px, full c contracted) ----
    ss += __shfl_xor(ss, 16);
    ss += __shfl_xor(ss, 32);
    float iv = 1.0f / fmaxf(sqrtf(ss), EPSF);
    int px = pb + wid * 16 + m;
    if (quad == 0) invn[px] = iv;

    float lg[16];
    float M1 = -3.0e38f, M2 = -3.0e38f; int I1 = 0, I2 = 0;
#pragma unroll
    for (int kg = 0; kg < 4; ++kg)
#pragma unroll
        for (int r = 0; r < 4; ++r) {
            float v = acc[kg][r] * iv;
            lg[kg * 4 + r] = v;
            int kk = kg * 16 + quad * 4 + r;
            if (v > M1)      { M2 = M1; I2 = I1; M1 = v; I1 = kk; }
            else if (v > M2) { M2 = v; I2 = kk; }
        }
    // cross-quad butterfly merge of (top1, top2), ties -> lower index
#pragma unroll
    for (int st = 0; st < 2; ++st) {
        int d = 16 << st;
        float a1 = __shfl_xor(M1, d); int b1 = __shfl_xor(I1, d);
        float a2 = __shfl_xor(M2, d); int b2 = __shfl_xor(I2, d);
        if (a1 > M1 || (a1 == M1 && b1 < I1)) { M2 = M1; I2 = I1; M1 = a1; I1 = b1; }
        else if (a1 > M2 || (a1 == M2 && b1 < I2)) { M2 = a1; I2 = b1; }
        if (a2 > M1 || (a2 == M1 && b2 < I1)) { M2 = M1; I2 = I1; M1 = a2; I1 = b2; }
        else if (a2 > M2 || (a2 == M2 && b2 < I2)) { M2 = a2; I2 = b2; }
    }

    float es = 0.f;
#pragma unroll
    for (int q = 0; q < 16; ++q) { float e = __expf(lg[q] - M1); lg[q] = e; es += e; }
    es += __shfl_xor(es, 16);
    es += __shfl_xor(es, 32);
    float rs = 1.0f / es;

    float4* sp = (float4*)(soft + (size_t)px * KK + quad * 4);
#pragma unroll
    for (int kg = 0; kg < 4; ++kg) {
        float4 o;
        o.x = lg[kg * 4 + 0] * rs; o.y = lg[kg * 4 + 1] * rs;
        o.z = lg[kg * 4 + 2] * rs; o.w = lg[kg * 4 + 3] * rs;
        sp[kg * 4] = o;     // soft[px*64 + kg*16 + quad*4 .. +3]
    }
    if (quad == 0) keep[px] = (1ull << I1) | (1ull << I2);
}

// ---------------------------------------------------------------- k2: weight = soft*cnt*border^4*invn[l]; S[k] += unscaled.
// Emits w2^T pre-split hi/lo bf16 planes in k3's A-fragment order; one 16B store per plane.
__global__ __launch_bounds__(256) void k2_weight(const float* __restrict__ soft,
                                                 const ull* __restrict__ keep,
                                                 const float* __restrict__ invn,
                                                 float* __restrict__ S,
                                                 ushort* __restrict__ w2t_hi,
                                                 ushort* __restrict__ w2t_lo) {
    __shared__ float sred[4][64];
    int t = threadIdx.x, lane = t & 63, wid = t >> 6;
    int l0 = blockIdx.x * 32 + wid * 8;
    float sk = 0.f;
    bf16x8 hv, lv;
#pragma unroll
    for (int p = 0; p < 8; ++p) {
        int l = l0 + p;                           // wave-uniform
        int i = l / WW, j = l % WW;
        int m = min(min(i, HH - 1 - i), min(j, WW - 1 - j));
        float bm = (float)m; bm *= bm; bm *= bm;  // m^4
        int cnt = 0;
#pragma unroll
        for (int di = -1; di <= 1; ++di) {
            int ii = i + di;
            if (ii < 0 || ii >= HH) continue;
#pragma unroll
            for (int dj = -1; dj <= 1; ++dj) {
                int jj = j + dj;
                if (jj < 0 || jj >= WW) continue;
                ull nb = keep[ii * WW + jj];      // uniform -> s_load
                cnt += (int)((nb >> lane) & 1ull);
            }
        }
        float v = soft[(size_t)l * KK + lane];    // coalesced 256B
        float u = v * (float)cnt * bm;            // unscaled weight
        sk += u;
        float w2v = u * invn[l];
        ushort h, lo;
        split2(w2v, h, lo);
        hv[p] = (short)h; lv[p] = (short)lo;
    }
    size_t off = (size_t)((((l0 >> 5) * 4 + (lane >> 4)) * 64 + ((l0 >> 3) & 3) * 16 + (lane & 15)) * 8);
    *(bf16x8*)(w2t_hi + off) = hv;
    *(bf16x8*)(w2t_lo + off) = lv;
    sred[wid][lane] = sk;
    __syncthreads();
    if (wid == 0)
        atomicAdd(&S[lane], sred[0][lane] + sred[1][lane] + sred[2][lane] + sred[3][lane]);
}

// ---------------------------------------------------------------- k3: MFMA GEMM, zero LDS / zero barriers.
// partials[ch][k][c] = sum_{l in chunk} w2[l][k] * x[c][l]
// A-frags: direct b128 loads from k2's fragment-ordered w2t hi/lo planes.
// B-frags: direct float4 x2 loads from row-major x + in-register 2-way split.
__global__ __launch_bounds__(256) void k3_mfma(const ushort* __restrict__ w2t_hi,
                                               const ushort* __restrict__ w2t_lo,
                                               const float* __restrict__ x,
                                               float* __restrict__ partials) {
    int chunk = blockIdx.x;             // 0..191
    int c0 = blockIdx.y * 128;          // 0..3
    int l0 = chunk * CHUNKL;
    int t = threadIdx.x, lane = t & 63, wid = t >> 6;
    int m = lane & 15, quad = lane >> 4;

    f32x4 acc[4][2];
#pragma unroll
    for (int kg = 0; kg < 4; ++kg)
#pragma unroll
        for (int cg = 0; cg < 2; ++cg) acc[kg][cg] = (f32x4){0.f, 0.f, 0.f, 0.f};

    const float* xb = x + (size_t)(c0 + wid * 32 + m) * LL + l0 + quad * 8;

#pragma unroll
    for (int lb = 0; lb < CHUNKL; lb += 32) {
        int lstep = (l0 + lb) >> 5;
        // ---- A frags: one b128/lane per (kg, plane) ----
        bf16x8 Ah[4], Al[4];
#pragma unroll
        for (int kg = 0; kg < 4; ++kg) {
            size_t off = (size_t)(((lstep * 4 + kg) * 64 + lane) * 8);
            Ah[kg] = *(const bf16x8*)(w2t_hi + off);
            Al[kg] = *(const bf16x8*)(w2t_lo + off);
        }
        // ---- B frags: direct loads + in-register split ----
        bf16x8 Bh[2], Bl[2];
#pragma unroll
        for (int cg = 0; cg < 2; ++cg) {
            const float* xr = xb + (size_t)(cg * 16) * LL + lb;
            float4 v0 = *(const float4*)xr;
            float4 v1 = *(const float4*)(xr + 4);
            float vv[8] = {v0.x, v0.y, v0.z, v0.w, v1.x, v1.y, v1.z, v1.w};
#pragma unroll
            for (int j = 0; j < 8; ++j) {
                ushort h, lo;
                split2(vv[j], h, lo);
                Bh[cg][j] = (short)h; Bl[cg][j] = (short)lo;
            }
        }
        // ---- 3-term MFMA ----
#pragma unroll
        for (int cg = 0; cg < 2; ++cg)
#pragma unroll
            for (int kg = 0; kg < 4; ++kg) {
                acc[kg][cg] = __builtin_amdgcn_mfma_f32_16x16x32_bf16(Ah[kg], Bh[cg], acc[kg][cg], 0, 0, 0);
                acc[kg][cg] = __builtin_amdgcn_mfma_f32_16x16x32_bf16(Ah[kg], Bl[cg], acc[kg][cg], 0, 0, 0);
                acc[kg][cg] = __builtin_amdgcn_mfma_f32_16x16x32_bf16(Al[kg], Bh[cg], acc[kg][cg], 0, 0, 0);
            }
    }
    // ---- store: D row = kg*16 + quad*4 + r, col = c0 + wid*32 + cg*16 + m ----
    float* pp = partials + (size_t)chunk * KK * CC;
#pragma unroll
    for (int kg = 0; kg < 4; ++kg)
#pragma unroll
        for (int cg = 0; cg < 2; ++cg) {
            int cout = c0 + wid * 32 + cg * 16 + m;
#pragma unroll
            for (int r = 0; r < 4; ++r) {
                int kout = kg * 16 + quad * 4 + r;
                pp[(size_t)kout * CC + cout] = acc[kg][cg][r];
            }
        }
}

// ---------------------------------------------------------------- k4a: reduce partials -> vlad, rowsq atomic
__global__ __launch_bounds__(512) void k4a_reduce(const float* __restrict__ partials,
                                                  const float* __restrict__ S,
                                                  const float* __restrict__ cent,
                                                  float* __restrict__ vlad,
                                                  float* __restrict__ rowsq) {
    __shared__ float red[512];
    int k = blockIdx.x;
    int ci = threadIdx.x & 127;
    int c = blockIdx.y * 128 + ci;
    int q = threadIdx.x >> 7;                       // 0..3
    const float* pk = partials + (size_t)q * (NCHUNK / 4) * KK * CC + (size_t)k * CC + c;
    float s0 = 0.f, s1 = 0.f, s2 = 0.f, s3 = 0.f;
    for (int ch = 0; ch < NCHUNK / 4; ch += 4) {
        s0 += pk[(size_t)(ch + 0) * KK * CC];
        s1 += pk[(size_t)(ch + 1) * KK * CC];
        s2 += pk[(size_t)(ch + 2) * KK * CC];
        s3 += pk[(size_t)(ch + 3) * KK * CC];
    }
    red[threadIdx.x] = (s0 + s1) + (s2 + s3);
    __syncthreads();
    float vsq = 0.f;
    if (q == 0) {
        float v = red[ci] + red[ci + 128] + red[ci + 256] + red[ci + 384];
        v -= S[k] * cent[k * CC + c];
        vlad[k * CC + c] = v;
        vsq = v * v;
    }
    __syncthreads();
    red[threadIdx.x] = vsq;
    __syncthreads();
    for (int off = 256; off > 0; off >>= 1) {
        if (threadIdx.x < off) red[threadIdx.x] += red[threadIdx.x + off];
        __syncthreads();
    }
    if (threadIdx.x == 0) atomicAdd(&rowsq[k], red[0]);
}

// ---------------------------------------------------------------- k4c: out = vlad * rn[k], rn computed inline from rowsq
__global__ __launch_bounds__(256) void k4c_finish(const float* __restrict__ vlad,
                                                  const float* __restrict__ rowsq,
                                                  float* __restrict__ out) {
    __shared__ float rns[64];
    int t = threadIdx.x;
    if (t < 64) {
        float tot = rowsq[t];
        float r = 1.0f / fmaxf(sqrtf(tot), EPSF);
        float contrib = tot * r * r;
#pragma unroll
        for (int off = 32; off; off >>= 1) contrib += __shfl_xor(contrib, off, 64);
        float ginv = 1.0f / fmaxf(sqrtf(contrib), EPSF);
        rns[t] = r * ginv;
    }
    __syncthreads();
    int idx4 = blockIdx.x * 256 + t;               // 8192 float4s
    int k = idx4 >> 7;
    float s = rns[k];
    float4 v = ((const float4*)vlad)[idx4];
    v.x *= s; v.y *= s; v.z *= s; v.w *= s;
    ((float4*)out)[idx4] = v;
}

// ----------------------------------------------------------------
extern "C" void kernel_launch(void* const* d_in, const int* in_sizes, int n_in,
                              void* d_out, int out_size, void* d_ws, size_t ws_size,
                              hipStream_t stream) {
    const float* x      = (const float*)d_in[0];   // (512,192,192)
    const float* conv_w = (const float*)d_in[1];   // (64,512)
    const float* cent   = (const float*)d_in[2];   // (64,512)
    float* out = (float*)d_out;                    // 32768 fp32

    float* ws    = (float*)d_ws;
    ushort* Whi  = (ushort*)ws;                     // 32768 ushorts (fragment-ordered)
    ushort* Wmid = Whi + 32768;
    ushort* Wlo  = Wmid + 32768;                    // 3 x 64KB = 49152 floats total
    float* soft  = ws + 49152;                      // KK*LL
    float* invn  = soft + (size_t)KK * LL;          // 36864
    float* S     = invn + LL;                       // 64
    float* rowsq = S + KK;                          // 64  (S..rowsq contiguous 128 floats)
    float* vlad  = rowsq + KK;                      // 32768
    ull*   keep  = (ull*)(vlad + 32768);            // LL u64
    ushort* w2t_hi = (ushort*)(keep + LL);          // LL*KK ushorts (4.7 MB), fragment-ordered
    ushort* w2t_lo = w2t_hi + (size_t)LL * KK;      // LL*KK ushorts
    float* partials = (float*)(w2t_lo + (size_t)LL * KK);  // NCHUNK*KK*CC floats (25.2 MB)

    k0_prep<<<(KK * CC) / 256, 256, 0, stream>>>(conv_w, Whi, Wmid, Wlo, S);
    k1_logits<<<LL / 64, 256, 0, stream>>>(x, Whi, Wmid, Wlo, soft, invn, keep);
    k2_weight<<<LL / 32, 256, 0, stream>>>(soft, keep, invn, S, w2t_hi, w2t_lo);
    k3_mfma<<<dim3(NCHUNK, 4), 256, 0, stream>>>(w2t_hi, w2t_lo, x, partials);
    k4a_reduce<<<dim3(KK, 4), 512, 0, stream>>>(partials, S, cent, vlad, rowsq);
    k4c_finish<<<(KK * CC / 4) / 256, 256, 0, stream>>>(vlad, rowsq, out);
}

// Round 7
// 189.061 us; speedup vs baseline: 1.0808x; 1.0808x over previous
//
#include <hip/hip_runtime.h>

#define HH 192
#define WW 192
#define LL (HH * WW)   // 36864
#define CC 512
#define KK 64
#define EPSF 1e-12f
typedef unsigned long long ull;
typedef unsigned int uint;
typedef unsigned short ushort;

// k3 decomposition
#define NCHUNK 192
#define CHUNKL (LL / NCHUNK)   // 192

typedef short bf16x8 __attribute__((ext_vector_type(8)));
typedef float f32x4 __attribute__((ext_vector_type(4)));

// ---------------------------------------------------------------- async global->LDS, 16B per lane
__device__ __forceinline__ void gl16(const void* g, void* l) {
    __builtin_amdgcn_global_load_lds((const __attribute__((address_space(1))) void*)g,
                                     (__attribute__((address_space(3))) void*)l, 16, 0, 0);
}

// ---------------------------------------------------------------- fp32 -> 3-way bf16 split (hi/mid/lo, truncation; exact residuals)
__device__ inline void split3(float v, ushort& h, ushort& md, ushort& lo) {
    uint b  = __float_as_uint(v);
    uint hb = b & 0xFFFF0000u;
    float r1 = v - __uint_as_float(hb);          // exact
    uint mb = __float_as_uint(r1) & 0xFFFF0000u;
    float r2 = r1 - __uint_as_float(mb);         // exact
    uint lb = __float_as_uint(r2) & 0xFFFF0000u;
    h = (ushort)(hb >> 16); md = (ushort)(mb >> 16); lo = (ushort)(lb >> 16);
}

// ---------------------------------------------------------------- fp32 -> 2-way bf16 split (hi + residual lo)
__device__ inline void split2(float v, ushort& h, ushort& lo) {
    uint b  = __float_as_uint(v);
    uint hb = b & 0xFFFF0000u;
    float r = v - __uint_as_float(hb);           // exact
    h = (ushort)(hb >> 16); lo = (ushort)(__float_as_uint(r) >> 16);
}

// ---------------------------------------------------------------- k0: pre-split conv_w into fragment-ordered bf16 hi/mid/lo arrays.
// Fragment order: element W[kg*16+m][s*32 + quad*8 + j] -> ushort index ((s*4+kg)*64 + quad*16 + m)*8 + j
// so the W-slice for step s, kg is a contiguous 1KB block (64 lanes x 16B) -> one gl16.
__global__ __launch_bounds__(256) void k0_prep(const float* __restrict__ w,
                                               ushort* __restrict__ Whi,
                                               ushort* __restrict__ Wmid,
                                               ushort* __restrict__ Wlo,
                                               float* __restrict__ Szero) {
    int idx = blockIdx.x * 256 + threadIdx.x;   // 32768 = KK*CC
    int k = idx >> 9;
    int c = idx & 511;
    int s = c >> 5, w32 = c & 31, quad = w32 >> 3, j = w32 & 7;
    int kg = k >> 4, m = k & 15;
    int dst = (((s * 4 + kg) * 4 + quad) * 16 + m) * 8 + j;
    float v = w[idx];
    ushort h, md, lo;
    split3(v, h, md, lo);
    Whi[dst] = h; Wmid[dst] = md; Wlo[dst] = lo;
    if (blockIdx.x == 0 && threadIdx.x < 128) Szero[threadIdx.x] = 0.f;  // S[64]+rowsq[64]
}

// ---------------------------------------------------------------- k1: MFMA logits GEMM + fused norm/softmax/top2.
// v6: FULL m97 recipe — BOTH operands staged via global_load_lds, fragments via ds_read.
// Round-6 diagnosis: VGPR_Count=56 proves the compiler never batches 12 direct-global A-frag
// loads (needs 48+ VGPR); it re-serializes load->MFMA chains at L2 latency each iteration.
// LDS->MFMA is the path hipcc schedules near-optimally (fine-grained lgkmcnt, m97/r109).
// 576 blocks x 256 thr (4 waves). Block owns 64 px; wave w owns px [pb+16w,+16); full c=512.
// Per 32-c step: stage W-slice 12KB (12 x 1KB chunks, 3 per wave) + x-tile 8KB, double-buffered
// (40KB LDS). A-frags: ds_read_b128 at lane*16B (2 lanes/bank = conflict-free). Inner loop per
// kg keeps only 3 A-frags live -> no register cliff.
// 6-term triple-bf16 MFMA => ~2^-24 rel err (fp32-equivalent) so top-2 SET selection is stable.
__global__ __launch_bounds__(256) void k1_logits(const float* __restrict__ x,
                                                 const ushort* __restrict__ Whi,
                                                 const ushort* __restrict__ Wmid,
                                                 const ushort* __restrict__ Wlo,
                                                 float* __restrict__ soft,
                                                 float* __restrict__ invn,
                                                 ull* __restrict__ keep) {
    __shared__ ushort wl[2][12][512];   // 24 KB: W chunks [buf][plane*4+kg][lane*8]
    __shared__ float xs[2][32][64];     // 16 KB: x tile [buf][c-row][px]
    int t = threadIdx.x, lane = t & 63, wid = t >> 6;   // wid 0..3 = px-group
    int m = lane & 15, quad = lane >> 4;
    int pb = blockIdx.x * 64;

    f32x4 acc[4];
#pragma unroll
    for (int kg = 0; kg < 4; ++kg) acc[kg] = (f32x4){0.f, 0.f, 0.f, 0.f};
    float ss = 0.f;

    const ushort* Wp[3] = {Whi, Wmid, Wlo};
    // wave w stages x rows [4w,4w+4) and [16+4w,16+4w+4) of the 32-row step tile
    const float* gbase = x + (size_t)(4 * wid + quad) * LL + pb + m * 4;

    // ---- prologue: stage step 0 into buf 0 ----
    gl16(gbase, &xs[0][4 * wid][0]);
    gl16(gbase + (size_t)16 * LL, &xs[0][16 + 4 * wid][0]);
#pragma unroll
    for (int q = 0; q < 3; ++q) {
        int ch = 3 * wid + q;                  // 0..11: plane = ch>>2, kg = ch&3
        gl16(Wp[ch >> 2] + (size_t)(((0 * 4 + (ch & 3)) * 64 + lane) * 8), &wl[0][ch][(size_t)lane * 8]);
    }

    int cur = 0;
#pragma unroll
    for (int s = 0; s < 16; ++s) {
        __syncthreads();   // drains vmcnt: buf[cur] staged; prev reads of buf[cur^1] done
        if (s < 15) {
            const float* g = gbase + (size_t)(s + 1) * 32 * LL;
            gl16(g, &xs[cur ^ 1][4 * wid][0]);
            gl16(g + (size_t)16 * LL, &xs[cur ^ 1][16 + 4 * wid][0]);
#pragma unroll
            for (int q = 0; q < 3; ++q) {
                int ch = 3 * wid + q;
                gl16(Wp[ch >> 2] + (size_t)((((s + 1) * 4 + (ch & 3)) * 64 + lane) * 8),
                     &wl[cur ^ 1][ch][(size_t)lane * 8]);
            }
        }
        // ---- B frag from LDS: lane (m,quad) reads x[quad*8+j][wid*16+m] ----
        float xv[8];
#pragma unroll
        for (int j = 0; j < 8; ++j) xv[j] = xs[cur][quad * 8 + j][wid * 16 + m];
        bf16x8 Bh, Bm, Bl;
#pragma unroll
        for (int j = 0; j < 8; ++j) {
            float v = xv[j];
            ss = fmaf(v, v, ss);
            ushort h, md, lo;
            split3(v, h, md, lo);
            Bh[j] = (short)h; Bm[j] = (short)md; Bl[j] = (short)lo;
        }
        // ---- per kg: 3 ds_read_b128 A-frags + 6-term MFMA (<=3 A-frags live) ----
#pragma unroll
        for (int kg = 0; kg < 4; ++kg) {
            bf16x8 Ah = *(const bf16x8*)&wl[cur][kg    ][(size_t)lane * 8];
            bf16x8 Am = *(const bf16x8*)&wl[cur][4 + kg][(size_t)lane * 8];
            bf16x8 Al = *(const bf16x8*)&wl[cur][8 + kg][(size_t)lane * 8];
            f32x4 a = acc[kg];
            a = __builtin_amdgcn_mfma_f32_16x16x32_bf16(Ah, Bh, a, 0, 0, 0);
            a = __builtin_amdgcn_mfma_f32_16x16x32_bf16(Ah, Bm, a, 0, 0, 0);
            a = __builtin_amdgcn_mfma_f32_16x16x32_bf16(Am, Bh, a, 0, 0, 0);
            a = __builtin_amdgcn_mfma_f32_16x16x32_bf16(Ah, Bl, a, 0, 0, 0);
            a = __builtin_amdgcn_mfma_f32_16x16x32_bf16(Al, Bh, a, 0, 0, 0);
            a = __builtin_amdgcn_mfma_f32_16x16x32_bf16(Am, Bm, a, 0, 0, 0);
            acc[kg] = a;
        }
        cur ^= 1;
    }

    // ---- epilogue: wave-local (each wave owns its 16 px, full c contracted) ----
    ss += __shfl_xor(ss, 16);
    ss += __shfl_xor(ss, 32);
    float iv = 1.0f / fmaxf(sqrtf(ss), EPSF);
    int px = pb + wid * 16 + m;
    if (quad == 0) invn[px] = iv;

    float lg[16];
    float M1 = -3.0e38f, M2 = -3.0e38f; int I1 = 0, I2 = 0;
#pragma unroll
    for (int kg = 0; kg < 4; ++kg)
#pragma unroll
        for (int r = 0; r < 4; ++r) {
            float v = acc[kg][r] * iv;
            lg[kg * 4 + r] = v;
            int kk = kg * 16 + quad * 4 + r;
            if (v > M1)      { M2 = M1; I2 = I1; M1 = v; I1 = kk; }
            else if (v > M2) { M2 = v; I2 = kk; }
        }
    // cross-quad butterfly merge of (top1, top2), ties -> lower index
#pragma unroll
    for (int st = 0; st < 2; ++st) {
        int d = 16 << st;
        float a1 = __shfl_xor(M1, d); int b1 = __shfl_xor(I1, d);
        float a2 = __shfl_xor(M2, d); int b2 = __shfl_xor(I2, d);
        if (a1 > M1 || (a1 == M1 && b1 < I1)) { M2 = M1; I2 = I1; M1 = a1; I1 = b1; }
        else if (a1 > M2 || (a1 == M2 && b1 < I2)) { M2 = a1; I2 = b1; }
        if (a2 > M1 || (a2 == M1 && b2 < I1)) { M2 = M1; I2 = I1; M1 = a2; I1 = b2; }
        else if (a2 > M2 || (a2 == M2 && b2 < I2)) { M2 = a2; I2 = b2; }
    }

    float es = 0.f;
#pragma unroll
    for (int q = 0; q < 16; ++q) { float e = __expf(lg[q] - M1); lg[q] = e; es += e; }
    es += __shfl_xor(es, 16);
    es += __shfl_xor(es, 32);
    float rs = 1.0f / es;

    float4* sp = (float4*)(soft + (size_t)px * KK + quad * 4);
#pragma unroll
    for (int kg = 0; kg < 4; ++kg) {
        float4 o;
        o.x = lg[kg * 4 + 0] * rs; o.y = lg[kg * 4 + 1] * rs;
        o.z = lg[kg * 4 + 2] * rs; o.w = lg[kg * 4 + 3] * rs;
        sp[kg * 4] = o;     // soft[px*64 + kg*16 + quad*4 .. +3]
    }
    if (quad == 0) keep[px] = (1ull << I1) | (1ull << I2);
}

// ---------------------------------------------------------------- k2: weight = soft*cnt*border^4*invn[l]; S[k] += unscaled.
// Emits w2^T pre-split hi/lo bf16 planes in k3's A-fragment order; one 16B store per plane.
__global__ __launch_bounds__(256) void k2_weight(const float* __restrict__ soft,
                                                 const ull* __restrict__ keep,
                                                 const float* __restrict__ invn,
                                                 float* __restrict__ S,
                                                 ushort* __restrict__ w2t_hi,
                                                 ushort* __restrict__ w2t_lo) {
    __shared__ float sred[4][64];
    int t = threadIdx.x, lane = t & 63, wid = t >> 6;
    int l0 = blockIdx.x * 32 + wid * 8;
    float sk = 0.f;
    bf16x8 hv, lv;
#pragma unroll
    for (int p = 0; p < 8; ++p) {
        int l = l0 + p;                           // wave-uniform
        int i = l / WW, j = l % WW;
        int m = min(min(i, HH - 1 - i), min(j, WW - 1 - j));
        float bm = (float)m; bm *= bm; bm *= bm;  // m^4
        int cnt = 0;
#pragma unroll
        for (int di = -1; di <= 1; ++di) {
            int ii = i + di;
            if (ii < 0 || ii >= HH) continue;
#pragma unroll
            for (int dj = -1; dj <= 1; ++dj) {
                int jj = j + dj;
                if (jj < 0 || jj >= WW) continue;
                ull nb = keep[ii * WW + jj];      // uniform -> s_load
                cnt += (int)((nb >> lane) & 1ull);
            }
        }
        float v = soft[(size_t)l * KK + lane];    // coalesced 256B
        float u = v * (float)cnt * bm;            // unscaled weight
        sk += u;
        float w2v = u * invn[l];
        ushort h, lo;
        split2(w2v, h, lo);
        hv[p] = (short)h; lv[p] = (short)lo;
    }
    size_t off = (size_t)((((l0 >> 5) * 4 + (lane >> 4)) * 64 + ((l0 >> 3) & 3) * 16 + (lane & 15)) * 8);
    *(bf16x8*)(w2t_hi + off) = hv;
    *(bf16x8*)(w2t_lo + off) = lv;
    sred[wid][lane] = sk;
    __syncthreads();
    if (wid == 0)
        atomicAdd(&S[lane], sred[0][lane] + sred[1][lane] + sred[2][lane] + sred[3][lane]);
}

// ---------------------------------------------------------------- k3: MFMA GEMM, zero LDS / zero barriers.
// partials[ch][k][c] = sum_{l in chunk} w2[l][k] * x[c][l]
// A-frags: direct b128 loads from k2's fragment-ordered w2t hi/lo planes.
// B-frags: direct float4 x2 loads from row-major x + in-register 2-way split.
__global__ __launch_bounds__(256) void k3_mfma(const ushort* __restrict__ w2t_hi,
                                               const ushort* __restrict__ w2t_lo,
                                               const float* __restrict__ x,
                                               float* __restrict__ partials) {
    int chunk = blockIdx.x;             // 0..191
    int c0 = blockIdx.y * 128;          // 0..3
    int l0 = chunk * CHUNKL;
    int t = threadIdx.x, lane = t & 63, wid = t >> 6;
    int m = lane & 15, quad = lane >> 4;

    f32x4 acc[4][2];
#pragma unroll
    for (int kg = 0; kg < 4; ++kg)
#pragma unroll
        for (int cg = 0; cg < 2; ++cg) acc[kg][cg] = (f32x4){0.f, 0.f, 0.f, 0.f};

    const float* xb = x + (size_t)(c0 + wid * 32 + m) * LL + l0 + quad * 8;

#pragma unroll
    for (int lb = 0; lb < CHUNKL; lb += 32) {
        int lstep = (l0 + lb) >> 5;
        // ---- A frags: one b128/lane per (kg, plane) ----
        bf16x8 Ah[4], Al[4];
#pragma unroll
        for (int kg = 0; kg < 4; ++kg) {
            size_t off = (size_t)(((lstep * 4 + kg) * 64 + lane) * 8);
            Ah[kg] = *(const bf16x8*)(w2t_hi + off);
            Al[kg] = *(const bf16x8*)(w2t_lo + off);
        }
        // ---- B frags: direct loads + in-register split ----
        bf16x8 Bh[2], Bl[2];
#pragma unroll
        for (int cg = 0; cg < 2; ++cg) {
            const float* xr = xb + (size_t)(cg * 16) * LL + lb;
            float4 v0 = *(const float4*)xr;
            float4 v1 = *(const float4*)(xr + 4);
            float vv[8] = {v0.x, v0.y, v0.z, v0.w, v1.x, v1.y, v1.z, v1.w};
#pragma unroll
            for (int j = 0; j < 8; ++j) {
                ushort h, lo;
                split2(vv[j], h, lo);
                Bh[cg][j] = (short)h; Bl[cg][j] = (short)lo;
            }
        }
        // ---- 3-term MFMA ----
#pragma unroll
        for (int cg = 0; cg < 2; ++cg)
#pragma unroll
            for (int kg = 0; kg < 4; ++kg) {
                acc[kg][cg] = __builtin_amdgcn_mfma_f32_16x16x32_bf16(Ah[kg], Bh[cg], acc[kg][cg], 0, 0, 0);
                acc[kg][cg] = __builtin_amdgcn_mfma_f32_16x16x32_bf16(Ah[kg], Bl[cg], acc[kg][cg], 0, 0, 0);
                acc[kg][cg] = __builtin_amdgcn_mfma_f32_16x16x32_bf16(Al[kg], Bh[cg], acc[kg][cg], 0, 0, 0);
            }
    }
    // ---- store: D row = kg*16 + quad*4 + r, col = c0 + wid*32 + cg*16 + m ----
    float* pp = partials + (size_t)chunk * KK * CC;
#pragma unroll
    for (int kg = 0; kg < 4; ++kg)
#pragma unroll
        for (int cg = 0; cg < 2; ++cg) {
            int cout = c0 + wid * 32 + cg * 16 + m;
#pragma unroll
            for (int r = 0; r < 4; ++r) {
                int kout = kg * 16 + quad * 4 + r;
                pp[(size_t)kout * CC + cout] = acc[kg][cg][r];
            }
        }
}

// ---------------------------------------------------------------- k4a: reduce partials -> vlad, rowsq atomic
__global__ __launch_bounds__(512) void k4a_reduce(const float* __restrict__ partials,
                                                  const float* __restrict__ S,
                                                  const float* __restrict__ cent,
                                                  float* __restrict__ vlad,
                                                  float* __restrict__ rowsq) {
    __shared__ float red[512];
    int k = blockIdx.x;
    int ci = threadIdx.x & 127;
    int c = blockIdx.y * 128 + ci;
    int q = threadIdx.x >> 7;                       // 0..3
    const float* pk = partials + (size_t)q * (NCHUNK / 4) * KK * CC + (size_t)k * CC + c;
    float s0 = 0.f, s1 = 0.f, s2 = 0.f, s3 = 0.f;
    for (int ch = 0; ch < NCHUNK / 4; ch += 4) {
        s0 += pk[(size_t)(ch + 0) * KK * CC];
        s1 += pk[(size_t)(ch + 1) * KK * CC];
        s2 += pk[(size_t)(ch + 2) * KK * CC];
        s3 += pk[(size_t)(ch + 3) * KK * CC];
    }
    red[threadIdx.x] = (s0 + s1) + (s2 + s3);
    __syncthreads();
    float vsq = 0.f;
    if (q == 0) {
        float v = red[ci] + red[ci + 128] + red[ci + 256] + red[ci + 384];
        v -= S[k] * cent[k * CC + c];
        vlad[k * CC + c] = v;
        vsq = v * v;
    }
    __syncthreads();
    red[threadIdx.x] = vsq;
    __syncthreads();
    for (int off = 256; off > 0; off >>= 1) {
        if (threadIdx.x < off) red[threadIdx.x] += red[threadIdx.x + off];
        __syncthreads();
    }
    if (threadIdx.x == 0) atomicAdd(&rowsq[k], red[0]);
}

// ---------------------------------------------------------------- k4c: out = vlad * rn[k], rn computed inline from rowsq
__global__ __launch_bounds__(256) void k4c_finish(const float* __restrict__ vlad,
                                                  const float* __restrict__ rowsq,
                                                  float* __restrict__ out) {
    __shared__ float rns[64];
    int t = threadIdx.x;
    if (t < 64) {
        float tot = rowsq[t];
        float r = 1.0f / fmaxf(sqrtf(tot), EPSF);
        float contrib = tot * r * r;
#pragma unroll
        for (int off = 32; off; off >>= 1) contrib += __shfl_xor(contrib, off, 64);
        float ginv = 1.0f / fmaxf(sqrtf(contrib), EPSF);
        rns[t] = r * ginv;
    }
    __syncthreads();
    int idx4 = blockIdx.x * 256 + t;               // 8192 float4s
    int k = idx4 >> 7;
    float s = rns[k];
    float4 v = ((const float4*)vlad)[idx4];
    v.x *= s; v.y *= s; v.z *= s; v.w *= s;
    ((float4*)out)[idx4] = v;
}

// ----------------------------------------------------------------
extern "C" void kernel_launch(void* const* d_in, const int* in_sizes, int n_in,
                              void* d_out, int out_size, void* d_ws, size_t ws_size,
                              hipStream_t stream) {
    const float* x      = (const float*)d_in[0];   // (512,192,192)
    const float* conv_w = (const float*)d_in[1];   // (64,512)
    const float* cent   = (const float*)d_in[2];   // (64,512)
    float* out = (float*)d_out;                    // 32768 fp32

    float* ws    = (float*)d_ws;
    ushort* Whi  = (ushort*)ws;                     // 32768 ushorts (fragment-ordered)
    ushort* Wmid = Whi + 32768;
    ushort* Wlo  = Wmid + 32768;                    // 3 x 64KB = 49152 floats total
    float* soft  = ws + 49152;                      // KK*LL
    float* invn  = soft + (size_t)KK * LL;          // 36864
    float* S     = invn + LL;                       // 64
    float* rowsq = S + KK;                          // 64  (S..rowsq contiguous 128 floats)
    float* vlad  = rowsq + KK;                      // 32768
    ull*   keep  = (ull*)(vlad + 32768);            // LL u64
    ushort* w2t_hi = (ushort*)(keep + LL);          // LL*KK ushorts (4.7 MB), fragment-ordered
    ushort* w2t_lo = w2t_hi + (size_t)LL * KK;      // LL*KK ushorts
    float* partials = (float*)(w2t_lo + (size_t)LL * KK);  // NCHUNK*KK*CC floats (25.2 MB)

    k0_prep<<<(KK * CC) / 256, 256, 0, stream>>>(conv_w, Whi, Wmid, Wlo, S);
    k1_logits<<<LL / 64, 256, 0, stream>>>(x, Whi, Wmid, Wlo, soft, invn, keep);
    k2_weight<<<LL / 32, 256, 0, stream>>>(soft, keep, invn, S, w2t_hi, w2t_lo);
    k3_mfma<<<dim3(NCHUNK, 4), 256, 0, stream>>>(w2t_hi, w2t_lo, x, partials);
    k4a_reduce<<<dim3(KK, 4), 512, 0, stream>>>(partials, S, cent, vlad, rowsq);
    k4c_finish<<<(KK * CC / 4) / 256, 256, 0, stream>>>(vlad, rowsq, out);
}

// Round 8
// 187.641 us; speedup vs baseline: 1.0890x; 1.0076x over previous
//
#include <hip/hip_runtime.h>

#define HH 192
#define WW 192
#define LL (HH * WW)   // 36864
#define CC 512
#define KK 64
#define EPSF 1e-12f
typedef unsigned long long ull;
typedef unsigned int uint;
typedef unsigned short ushort;

// k3 decomposition
#define NCHUNK 192
#define CHUNKL (LL / NCHUNK)   // 192

typedef short bf16x8 __attribute__((ext_vector_type(8)));
typedef float f32x4 __attribute__((ext_vector_type(4)));

// ---------------------------------------------------------------- async global->LDS, 16B per lane
__device__ __forceinline__ void gl16(const void* g, void* l) {
    __builtin_amdgcn_global_load_lds((const __attribute__((address_space(1))) void*)g,
                                     (__attribute__((address_space(3))) void*)l, 16, 0, 0);
}

// ---------------------------------------------------------------- fp32 -> 3-way bf16 split (hi/mid/lo, truncation; exact residuals)
__device__ inline void split3(float v, ushort& h, ushort& md, ushort& lo) {
    uint b  = __float_as_uint(v);
    uint hb = b & 0xFFFF0000u;
    float r1 = v - __uint_as_float(hb);          // exact
    uint mb = __float_as_uint(r1) & 0xFFFF0000u;
    float r2 = r1 - __uint_as_float(mb);         // exact
    uint lb = __float_as_uint(r2) & 0xFFFF0000u;
    h = (ushort)(hb >> 16); md = (ushort)(mb >> 16); lo = (ushort)(lb >> 16);
}

// ---------------------------------------------------------------- fp32 -> 2-way bf16 split (hi + residual lo)
__device__ inline void split2(float v, ushort& h, ushort& lo) {
    uint b  = __float_as_uint(v);
    uint hb = b & 0xFFFF0000u;
    float r = v - __uint_as_float(hb);           // exact
    h = (ushort)(hb >> 16); lo = (ushort)(__float_as_uint(r) >> 16);
}

// ---------------------------------------------------------------- k0: pre-split conv_w into fragment-ordered bf16 hi/mid/lo arrays.
// Fragment order: element W[kg*16+m][s*32 + quad*8 + j] -> ushort index ((s*4+kg)*64 + quad*16 + m)*8 + j
// so the W-slice for step s, kg is a contiguous 1KB block (64 lanes x 16B) -> one gl16.
__global__ __launch_bounds__(256) void k0_prep(const float* __restrict__ w,
                                               ushort* __restrict__ Whi,
                                               ushort* __restrict__ Wmid,
                                               ushort* __restrict__ Wlo,
                                               float* __restrict__ Szero) {
    int idx = blockIdx.x * 256 + threadIdx.x;   // 32768 = KK*CC
    int k = idx >> 9;
    int c = idx & 511;
    int s = c >> 5, w32 = c & 31, quad = w32 >> 3, j = w32 & 7;
    int kg = k >> 4, m = k & 15;
    int dst = (((s * 4 + kg) * 4 + quad) * 16 + m) * 8 + j;
    float v = w[idx];
    ushort h, md, lo;
    split3(v, h, md, lo);
    Whi[dst] = h; Wmid[dst] = md; Wlo[dst] = lo;
    if (blockIdx.x == 0 && threadIdx.x < 128) Szero[threadIdx.x] = 0.f;  // S[64]+rowsq[64]
}

// ---------------------------------------------------------------- k1: MFMA logits GEMM + fused norm/softmax/top2.
// v6 (round-7, measured ~31 us): FULL m97 recipe — both operands staged via global_load_lds,
// fragments via ds_read; double-buffered, one barrier per 32-c step. UNCHANGED this round.
__global__ __launch_bounds__(256) void k1_logits(const float* __restrict__ x,
                                                 const ushort* __restrict__ Whi,
                                                 const ushort* __restrict__ Wmid,
                                                 const ushort* __restrict__ Wlo,
                                                 float* __restrict__ soft,
                                                 float* __restrict__ invn,
                                                 ull* __restrict__ keep) {
    __shared__ ushort wl[2][12][512];   // 24 KB: W chunks [buf][plane*4+kg][lane*8]
    __shared__ float xs[2][32][64];     // 16 KB: x tile [buf][c-row][px]
    int t = threadIdx.x, lane = t & 63, wid = t >> 6;   // wid 0..3 = px-group
    int m = lane & 15, quad = lane >> 4;
    int pb = blockIdx.x * 64;

    f32x4 acc[4];
#pragma unroll
    for (int kg = 0; kg < 4; ++kg) acc[kg] = (f32x4){0.f, 0.f, 0.f, 0.f};
    float ss = 0.f;

    const ushort* Wp[3] = {Whi, Wmid, Wlo};
    // wave w stages x rows [4w,4w+4) and [16+4w,16+4w+4) of the 32-row step tile
    const float* gbase = x + (size_t)(4 * wid + quad) * LL + pb + m * 4;

    // ---- prologue: stage step 0 into buf 0 ----
    gl16(gbase, &xs[0][4 * wid][0]);
    gl16(gbase + (size_t)16 * LL, &xs[0][16 + 4 * wid][0]);
#pragma unroll
    for (int q = 0; q < 3; ++q) {
        int ch = 3 * wid + q;                  // 0..11: plane = ch>>2, kg = ch&3
        gl16(Wp[ch >> 2] + (size_t)(((0 * 4 + (ch & 3)) * 64 + lane) * 8), &wl[0][ch][(size_t)lane * 8]);
    }

    int cur = 0;
#pragma unroll
    for (int s = 0; s < 16; ++s) {
        __syncthreads();   // drains vmcnt: buf[cur] staged; prev reads of buf[cur^1] done
        if (s < 15) {
            const float* g = gbase + (size_t)(s + 1) * 32 * LL;
            gl16(g, &xs[cur ^ 1][4 * wid][0]);
            gl16(g + (size_t)16 * LL, &xs[cur ^ 1][16 + 4 * wid][0]);
#pragma unroll
            for (int q = 0; q < 3; ++q) {
                int ch = 3 * wid + q;
                gl16(Wp[ch >> 2] + (size_t)((((s + 1) * 4 + (ch & 3)) * 64 + lane) * 8),
                     &wl[cur ^ 1][ch][(size_t)lane * 8]);
            }
        }
        // ---- B frag from LDS: lane (m,quad) reads x[quad*8+j][wid*16+m] ----
        float xv[8];
#pragma unroll
        for (int j = 0; j < 8; ++j) xv[j] = xs[cur][quad * 8 + j][wid * 16 + m];
        bf16x8 Bh, Bm, Bl;
#pragma unroll
        for (int j = 0; j < 8; ++j) {
            float v = xv[j];
            ss = fmaf(v, v, ss);
            ushort h, md, lo;
            split3(v, h, md, lo);
            Bh[j] = (short)h; Bm[j] = (short)md; Bl[j] = (short)lo;
        }
        // ---- per kg: 3 ds_read_b128 A-frags + 6-term MFMA (<=3 A-frags live) ----
#pragma unroll
        for (int kg = 0; kg < 4; ++kg) {
            bf16x8 Ah = *(const bf16x8*)&wl[cur][kg    ][(size_t)lane * 8];
            bf16x8 Am = *(const bf16x8*)&wl[cur][4 + kg][(size_t)lane * 8];
            bf16x8 Al = *(const bf16x8*)&wl[cur][8 + kg][(size_t)lane * 8];
            f32x4 a = acc[kg];
            a = __builtin_amdgcn_mfma_f32_16x16x32_bf16(Ah, Bh, a, 0, 0, 0);
            a = __builtin_amdgcn_mfma_f32_16x16x32_bf16(Ah, Bm, a, 0, 0, 0);
            a = __builtin_amdgcn_mfma_f32_16x16x32_bf16(Am, Bh, a, 0, 0, 0);
            a = __builtin_amdgcn_mfma_f32_16x16x32_bf16(Ah, Bl, a, 0, 0, 0);
            a = __builtin_amdgcn_mfma_f32_16x16x32_bf16(Al, Bh, a, 0, 0, 0);
            a = __builtin_amdgcn_mfma_f32_16x16x32_bf16(Am, Bm, a, 0, 0, 0);
            acc[kg] = a;
        }
        cur ^= 1;
    }

    // ---- epilogue: wave-local (each wave owns its 16 px, full c contracted) ----
    ss += __shfl_xor(ss, 16);
    ss += __shfl_xor(ss, 32);
    float iv = 1.0f / fmaxf(sqrtf(ss), EPSF);
    int px = pb + wid * 16 + m;
    if (quad == 0) invn[px] = iv;

    float lg[16];
    float M1 = -3.0e38f, M2 = -3.0e38f; int I1 = 0, I2 = 0;
#pragma unroll
    for (int kg = 0; kg < 4; ++kg)
#pragma unroll
        for (int r = 0; r < 4; ++r) {
            float v = acc[kg][r] * iv;
            lg[kg * 4 + r] = v;
            int kk = kg * 16 + quad * 4 + r;
            if (v > M1)      { M2 = M1; I2 = I1; M1 = v; I1 = kk; }
            else if (v > M2) { M2 = v; I2 = kk; }
        }
    // cross-quad butterfly merge of (top1, top2), ties -> lower index
#pragma unroll
    for (int st = 0; st < 2; ++st) {
        int d = 16 << st;
        float a1 = __shfl_xor(M1, d); int b1 = __shfl_xor(I1, d);
        float a2 = __shfl_xor(M2, d); int b2 = __shfl_xor(I2, d);
        if (a1 > M1 || (a1 == M1 && b1 < I1)) { M2 = M1; I2 = I1; M1 = a1; I1 = b1; }
        else if (a1 > M2 || (a1 == M2 && b1 < I2)) { M2 = a1; I2 = b1; }
        if (a2 > M1 || (a2 == M1 && b2 < I1)) { M2 = M1; I2 = I1; M1 = a2; I1 = b2; }
        else if (a2 > M2 || (a2 == M2 && b2 < I2)) { M2 = a2; I2 = b2; }
    }

    float es = 0.f;
#pragma unroll
    for (int q = 0; q < 16; ++q) { float e = __expf(lg[q] - M1); lg[q] = e; es += e; }
    es += __shfl_xor(es, 16);
    es += __shfl_xor(es, 32);
    float rs = 1.0f / es;

    float4* sp = (float4*)(soft + (size_t)px * KK + quad * 4);
#pragma unroll
    for (int kg = 0; kg < 4; ++kg) {
        float4 o;
        o.x = lg[kg * 4 + 0] * rs; o.y = lg[kg * 4 + 1] * rs;
        o.z = lg[kg * 4 + 2] * rs; o.w = lg[kg * 4 + 3] * rs;
        sp[kg * 4] = o;     // soft[px*64 + kg*16 + quad*4 .. +3]
    }
    if (quad == 0) keep[px] = (1ull << I1) | (1ull << I2);
}

// ---------------------------------------------------------------- k2: weight = soft*cnt*border^4*invn[l]; S[k] += unscaled.
// Emits w2^T pre-split hi/lo bf16 planes in k3's A-fragment order; one 16B store per plane.
__global__ __launch_bounds__(256) void k2_weight(const float* __restrict__ soft,
                                                 const ull* __restrict__ keep,
                                                 const float* __restrict__ invn,
                                                 float* __restrict__ S,
                                                 ushort* __restrict__ w2t_hi,
                                                 ushort* __restrict__ w2t_lo) {
    __shared__ float sred[4][64];
    int t = threadIdx.x, lane = t & 63, wid = t >> 6;
    int l0 = blockIdx.x * 32 + wid * 8;
    float sk = 0.f;
    bf16x8 hv, lv;
#pragma unroll
    for (int p = 0; p < 8; ++p) {
        int l = l0 + p;                           // wave-uniform
        int i = l / WW, j = l % WW;
        int m = min(min(i, HH - 1 - i), min(j, WW - 1 - j));
        float bm = (float)m; bm *= bm; bm *= bm;  // m^4
        int cnt = 0;
#pragma unroll
        for (int di = -1; di <= 1; ++di) {
            int ii = i + di;
            if (ii < 0 || ii >= HH) continue;
#pragma unroll
            for (int dj = -1; dj <= 1; ++dj) {
                int jj = j + dj;
                if (jj < 0 || jj >= WW) continue;
                ull nb = keep[ii * WW + jj];      // uniform -> s_load
                cnt += (int)((nb >> lane) & 1ull);
            }
        }
        float v = soft[(size_t)l * KK + lane];    // coalesced 256B
        float u = v * (float)cnt * bm;            // unscaled weight
        sk += u;
        float w2v = u * invn[l];
        ushort h, lo;
        split2(w2v, h, lo);
        hv[p] = (short)h; lv[p] = (short)lo;
    }
    size_t off = (size_t)((((l0 >> 5) * 4 + (lane >> 4)) * 64 + ((l0 >> 3) & 3) * 16 + (lane & 15)) * 8);
    *(bf16x8*)(w2t_hi + off) = hv;
    *(bf16x8*)(w2t_lo + off) = lv;
    sred[wid][lane] = sk;
    __syncthreads();
    if (wid == 0)
        atomicAdd(&S[lane], sred[0][lane] + sred[1][lane] + sred[2][lane] + sred[3][lane]);
}

// ---------------------------------------------------------------- k3: MFMA GEMM, m97 recipe (round-8).
// partials[ch][k][c] = sum_{l in chunk} w2[l][k] * x[c][l]
// Round-7 lesson (k1 46->31): direct-global MFMA operand loads get compiler-serialized at L2
// latency; LDS-staged fragments (gl16 + ds_read) are the path hipcc pipelines.
// Per 32-l step: stage A = w2t hi/lo frag-slices (8KB, 8x1KB chunks) and B = x[128c][32l] fp32
// (16KB) via global_load_lds, double-buffered (48KB LDS -> 3 blocks/CU, all 768 resident).
// B uses XOR-swizzle (G21/m173): linear LDS dest + pre-swizzled global SOURCE (phys granule g
// of row c holds logical l-granule g^(c&7)) + swizzled ds_read_b128 -> 8 words/bank (floor);
// unswizzled would idle half the banks (2x). Coalescing preserved (same 128B row segments).
// One barrier per step (k1-v6 pattern). Same 3-term split2 numerics as round 7.
__global__ __launch_bounds__(256) void k3_mfma(const ushort* __restrict__ w2t_hi,
                                               const ushort* __restrict__ w2t_lo,
                                               const float* __restrict__ x,
                                               float* __restrict__ partials) {
    __shared__ ushort wa[2][8][512];    // 16 KB: A chunks [buf][plane*4+kg][lane*8]
    __shared__ float  xb[2][128][32];   // 32 KB: B tile [buf][c][l] (source-swizzled)
    int chunk = blockIdx.x;             // 0..191
    int c0 = blockIdx.y * 128;          // 0..3
    int l0 = chunk * CHUNKL;
    int lsbase = chunk * (CHUNKL / 32); // first 32-l step index
    int t = threadIdx.x, lane = t & 63, wid = t >> 6;
    int m = lane & 15, quad = lane >> 4;

    f32x4 acc[4][2];
#pragma unroll
    for (int kg = 0; kg < 4; ++kg)
#pragma unroll
        for (int cg = 0; cg < 2; ++cg) acc[kg][cg] = (f32x4){0.f, 0.f, 0.f, 0.f};

    // B staging geometry: wave w covers rows [w*32, w*32+32); gl16 i covers rows w*32+8i..+8.
    // Lane: rowg = lane>>3 (row within 8-group), g = lane&7 (phys granule); source l is
    // the swizzled logical granule g^rowg (row&7 == rowg since group base = 0 mod 8).
    int rowg = lane >> 3, gph = lane & 7;
    int swzl = ((gph ^ rowg) * 4);

    // ---- prologue: stage step 0 into buf 0 ----
#pragma unroll
    for (int q = 0; q < 2; ++q) {
        int ch = 2 * wid + q;          // 0..7: plane = ch>>2, kg = ch&3
        const ushort* src = (ch < 4 ? w2t_hi : w2t_lo) + (size_t)(((lsbase * 4 + (ch & 3)) * 64 + lane) * 8);
        gl16(src, &wa[0][ch][(size_t)lane * 8]);
    }
#pragma unroll
    for (int i = 0; i < 4; ++i) {
        int row = wid * 32 + 8 * i + rowg;
        gl16(x + (size_t)(c0 + row) * LL + l0 + swzl, &xb[0][wid * 32 + 8 * i][0]);
    }

    int cur = 0;
#pragma unroll
    for (int st = 0; st < CHUNKL / 32; ++st) {
        __syncthreads();   // drains vmcnt: buf[cur] staged; prev reads of buf[cur^1] done
        if (st < CHUNKL / 32 - 1) {
#pragma unroll
            for (int q = 0; q < 2; ++q) {
                int ch = 2 * wid + q;
                const ushort* src = (ch < 4 ? w2t_hi : w2t_lo) +
                                    (size_t)((((lsbase + st + 1) * 4 + (ch & 3)) * 64 + lane) * 8);
                gl16(src, &wa[cur ^ 1][ch][(size_t)lane * 8]);
            }
#pragma unroll
            for (int i = 0; i < 4; ++i) {
                int row = wid * 32 + 8 * i + rowg;
                gl16(x + (size_t)(c0 + row) * LL + l0 + (st + 1) * 32 + swzl,
                     &xb[cur ^ 1][wid * 32 + 8 * i][0]);
            }
        }
        // ---- A frags: 8 ds_read_b128, conflict-free (2 lanes/bank) ----
        bf16x8 Ah[4], Al[4];
#pragma unroll
        for (int kg = 0; kg < 4; ++kg) {
            Ah[kg] = *(const bf16x8*)&wa[cur][kg    ][(size_t)lane * 8];
            Al[kg] = *(const bf16x8*)&wa[cur][4 + kg][(size_t)lane * 8];
        }
        // ---- B frags: 2x ds_read_b128 per cg at swizzled granules + in-register split ----
        bf16x8 Bh[2], Bl[2];
#pragma unroll
        for (int cg = 0; cg < 2; ++cg) {
            int crow = wid * 32 + cg * 16 + m;
            const float* xr = &xb[cur][crow][0];
            float4 v0 = *(const float4*)(xr + (((quad * 2    ) ^ (m & 7)) * 4));
            float4 v1 = *(const float4*)(xr + (((quad * 2 + 1) ^ (m & 7)) * 4));
            float vv[8] = {v0.x, v0.y, v0.z, v0.w, v1.x, v1.y, v1.z, v1.w};
#pragma unroll
            for (int j = 0; j < 8; ++j) {
                ushort h, lo;
                split2(vv[j], h, lo);
                Bh[cg][j] = (short)h; Bl[cg][j] = (short)lo;
            }
        }
        // ---- 3-term MFMA ----
#pragma unroll
        for (int cg = 0; cg < 2; ++cg)
#pragma unroll
            for (int kg = 0; kg < 4; ++kg) {
                acc[kg][cg] = __builtin_amdgcn_mfma_f32_16x16x32_bf16(Ah[kg], Bh[cg], acc[kg][cg], 0, 0, 0);
                acc[kg][cg] = __builtin_amdgcn_mfma_f32_16x16x32_bf16(Ah[kg], Bl[cg], acc[kg][cg], 0, 0, 0);
                acc[kg][cg] = __builtin_amdgcn_mfma_f32_16x16x32_bf16(Al[kg], Bh[cg], acc[kg][cg], 0, 0, 0);
            }
        cur ^= 1;
    }
    // ---- store: D row = kg*16 + quad*4 + r, col = c0 + wid*32 + cg*16 + m ----
    float* pp = partials + (size_t)chunk * KK * CC;
#pragma unroll
    for (int kg = 0; kg < 4; ++kg)
#pragma unroll
        for (int cg = 0; cg < 2; ++cg) {
            int cout = c0 + wid * 32 + cg * 16 + m;
#pragma unroll
            for (int r = 0; r < 4; ++r) {
                int kout = kg * 16 + quad * 4 + r;
                pp[(size_t)kout * CC + cout] = acc[kg][cg][r];
            }
        }
}

// ---------------------------------------------------------------- k4a: reduce partials -> vlad, rowsq atomic
__global__ __launch_bounds__(512) void k4a_reduce(const float* __restrict__ partials,
                                                  const float* __restrict__ S,
                                                  const float* __restrict__ cent,
                                                  float* __restrict__ vlad,
                                                  float* __restrict__ rowsq) {
    __shared__ float red[512];
    int k = blockIdx.x;
    int ci = threadIdx.x & 127;
    int c = blockIdx.y * 128 + ci;
    int q = threadIdx.x >> 7;                       // 0..3
    const float* pk = partials + (size_t)q * (NCHUNK / 4) * KK * CC + (size_t)k * CC + c;
    float s0 = 0.f, s1 = 0.f, s2 = 0.f, s3 = 0.f;
    for (int ch = 0; ch < NCHUNK / 4; ch += 4) {
        s0 += pk[(size_t)(ch + 0) * KK * CC];
        s1 += pk[(size_t)(ch + 1) * KK * CC];
        s2 += pk[(size_t)(ch + 2) * KK * CC];
        s3 += pk[(size_t)(ch + 3) * KK * CC];
    }
    red[threadIdx.x] = (s0 + s1) + (s2 + s3);
    __syncthreads();
    float vsq = 0.f;
    if (q == 0) {
        float v = red[ci] + red[ci + 128] + red[ci + 256] + red[ci + 384];
        v -= S[k] * cent[k * CC + c];
        vlad[k * CC + c] = v;
        vsq = v * v;
    }
    __syncthreads();
    red[threadIdx.x] = vsq;
    __syncthreads();
    for (int off = 256; off > 0; off >>= 1) {
        if (threadIdx.x < off) red[threadIdx.x] += red[threadIdx.x + off];
        __syncthreads();
    }
    if (threadIdx.x == 0) atomicAdd(&rowsq[k], red[0]);
}

// ---------------------------------------------------------------- k4c: out = vlad * rn[k], rn computed inline from rowsq
__global__ __launch_bounds__(256) void k4c_finish(const float* __restrict__ vlad,
                                                  const float* __restrict__ rowsq,
                                                  float* __restrict__ out) {
    __shared__ float rns[64];
    int t = threadIdx.x;
    if (t < 64) {
        float tot = rowsq[t];
        float r = 1.0f / fmaxf(sqrtf(tot), EPSF);
        float contrib = tot * r * r;
#pragma unroll
        for (int off = 32; off; off >>= 1) contrib += __shfl_xor(contrib, off, 64);
        float ginv = 1.0f / fmaxf(sqrtf(contrib), EPSF);
        rns[t] = r * ginv;
    }
    __syncthreads();
    int idx4 = blockIdx.x * 256 + t;               // 8192 float4s
    int k = idx4 >> 7;
    float s = rns[k];
    float4 v = ((const float4*)vlad)[idx4];
    v.x *= s; v.y *= s; v.z *= s; v.w *= s;
    ((float4*)out)[idx4] = v;
}

// ----------------------------------------------------------------
extern "C" void kernel_launch(void* const* d_in, const int* in_sizes, int n_in,
                              void* d_out, int out_size, void* d_ws, size_t ws_size,
                              hipStream_t stream) {
    const float* x      = (const float*)d_in[0];   // (512,192,192)
    const float* conv_w = (const float*)d_in[1];   // (64,512)
    const float* cent   = (const float*)d_in[2];   // (64,512)
    float* out = (float*)d_out;                    // 32768 fp32

    float* ws    = (float*)d_ws;
    ushort* Whi  = (ushort*)ws;                     // 32768 ushorts (fragment-ordered)
    ushort* Wmid = Whi + 32768;
    ushort* Wlo  = Wmid + 32768;                    // 3 x 64KB = 49152 floats total
    float* soft  = ws + 49152;                      // KK*LL
    float* invn  = soft + (size_t)KK * LL;          // 36864
    float* S     = invn + LL;                       // 64
    float* rowsq = S + KK;                          // 64  (S..rowsq contiguous 128 floats)
    float* vlad  = rowsq + KK;                      // 32768
    ull*   keep  = (ull*)(vlad + 32768);            // LL u64
    ushort* w2t_hi = (ushort*)(keep + LL);          // LL*KK ushorts (4.7 MB), fragment-ordered
    ushort* w2t_lo = w2t_hi + (size_t)LL * KK;      // LL*KK ushorts
    float* partials = (float*)(w2t_lo + (size_t)LL * KK);  // NCHUNK*KK*CC floats (25.2 MB)

    k0_prep<<<(KK * CC) / 256, 256, 0, stream>>>(conv_w, Whi, Wmid, Wlo, S);
    k1_logits<<<LL / 64, 256, 0, stream>>>(x, Whi, Wmid, Wlo, soft, invn, keep);
    k2_weight<<<LL / 32, 256, 0, stream>>>(soft, keep, invn, S, w2t_hi, w2t_lo);
    k3_mfma<<<dim3(NCHUNK, 4), 256, 0, stream>>>(w2t_hi, w2t_lo, x, partials);
    k4a_reduce<<<dim3(KK, 4), 512, 0, stream>>>(partials, S, cent, vlad, rowsq);
    k4c_finish<<<(KK * CC / 4) / 256, 256, 0, stream>>>(vlad, rowsq, out);
}